// Round 9
// baseline (828.732 us; speedup 1.0000x reference)
//
#include <hip/hip_runtime.h>
#include <math.h>

#define NB 256       // batch
#define HT 17
#define WT 17
#define HI 384
#define WI 384
#define LH 368
#define LW 368
#define NTEMPL 289   // HT*WT
#define TPAD 20      // padded template row width
#define BM 64        // output tile rows per block
#define BN 64        // output tile cols per block
#define NXB 6        // blocks per dim (6*64 = 384 covers 368 outputs)
#define NTILES 36    // blocks per batch
#define BGR 80       // staged bg rows  (64 + 16)
#define BGC 80       // staged bg cols  (64 + 16)
#define PHB 88       // bf16 pitch for bg hi/lo (16B-aligned rows, even bank spread)
#define RP 65        // f32 pitch for r1/r2 stat rows
#define TEMP_INV 25.0f
#define EPSV 1e-6f

typedef __attribute__((ext_vector_type(8))) short bf16x8;   // 8 bf16 = 4 VGPR (guide §3)
typedef __attribute__((ext_vector_type(4))) float f32x4;

__device__ __forceinline__ unsigned short f2bf(float x) {   // RNE f32->bf16
    unsigned u = __float_as_uint(x);
    u += 0x7FFF + ((u >> 16) & 1);
    return (unsigned short)(u >> 16);
}
__device__ __forceinline__ float bf2f(unsigned short h) {
    return __uint_as_float(((unsigned)h) << 16);
}

// ---------------- kernel 1: per-batch template normalization ----------------
__global__ __launch_bounds__(256) void tmpl_norm_kernel(
    const float* __restrict__ piece, float* __restrict__ tn) {
    int b = blockIdx.x;
    const float* x = piece + b * NTEMPL;
    int tid = threadIdx.x;
    int wid = tid >> 6, lane = tid & 63;

    float v0 = (tid < NTEMPL) ? x[tid] : 0.f;
    float v1 = (tid + 256 < NTEMPL) ? x[tid + 256] : 0.f;

    __shared__ float sred[4];
    float s = v0 + v1;
    #pragma unroll
    for (int o = 32; o > 0; o >>= 1) s += __shfl_down(s, o, 64);
    if (lane == 0) sred[wid] = s;
    __syncthreads();
    float mean = (sred[0] + sred[1] + sred[2] + sred[3]) * (1.0f / NTEMPL);

    float d0 = (tid < NTEMPL) ? (v0 - mean) : 0.f;
    float d1 = (tid + 256 < NTEMPL) ? (v1 - mean) : 0.f;
    float q = d0 * d0 + d1 * d1;
    __syncthreads();
    #pragma unroll
    for (int o = 32; o > 0; o >>= 1) q += __shfl_down(q, o, 64);
    if (lane == 0) sred[wid] = q;
    __syncthreads();
    float var = (sred[0] + sred[1] + sred[2] + sred[3]) * (1.0f / (NTEMPL - 1));
    float stdv = sqrtf(var);
    if (stdv < EPSV) stdv = EPSV;
    float inv = 1.0f / stdv;

    float* o = tn + b * (HT * TPAD);
    for (int sIdx = tid; sIdx < HT * TPAD; sIdx += 256) {
        int i = sIdx / TPAD, j = sIdx % TPAD;
        o[sIdx] = (j < WT) ? (x[i * WT + j] - mean) * inv : 0.f;
    }
}

// ---------------- kernel 2: MFMA correlation + stats + softmax partials -----------
// num(y, x0+n) = sum_i sum_kk A_i[m][kk] * B_i[kk][n], A_i = bg rows (M=y, K=32-col
// window), B_i[kk][n] = t(i, kk-n) (zero outside [0,17)). 3-term bf16 split:
// AhBh + AhBl + AlBh (lo*lo ~2^-18, dropped). MFMA 16x16x32_bf16; lane layouts:
// A row=l&15, k=(l>>4)*8+e; B col=l&15, k=(l>>4)*8+e; D col=l&15, row=(l>>4)*4+q
// (C/D m89-verified). Stats from hi+lo reconstruction (err ~2^-17, harmless).
struct SMainT {
    unsigned short bh[BGR][PHB];   // 14080 B  bg hi
    unsigned short bl[BGR][PHB];   // 14080 B  bg lo
    unsigned short Bh[17 * 512];   // 17408 B  B frag-major: [i][kchunk4][n16][e8]
    unsigned short Bl[17 * 512];   // 17408 B
};                                  // 62976 B total
struct SStatT {
    unsigned short pad0[BGR][PHB];
    unsigned short pad1[BGR][PHB];
    float r[BGR][RP];              // 20800 B, overlays Bh/Bl after main loop
};
union SU { SMainT m; SStatT s; };

__global__ __launch_bounds__(256, 2) void corr_kernel(
    const float* __restrict__ bgg, const float* __restrict__ tn,
    float* __restrict__ partials) {
    int blk = blockIdx.x;
    int b = blk / NTILES;
    int t = blk % NTILES;
    int y0 = (t / NXB) * BM;
    int x0 = (t % NXB) * BN;
    const float* img = bgg + (size_t)b * HI * WI;
    const float* tp  = tn + b * (HT * TPAD);

    __shared__ SU S;
    __shared__ float redm[4], redl[4], redy[4], redx[4];

    int tid = threadIdx.x;
    int wid = tid >> 6, lane = tid & 63;
    int lm = lane & 15, lk = lane >> 4;       // frag row/col + k-chunk
    int wy = wid >> 1, wx = wid & 1;
    int y0w = wy * 32, x0w = wx * 32;         // wave's 32x32 output quadrant

    // ---- stage bg as bf16 hi/lo (zero-filled OOB); 80 rows x 20 float4 ----
    for (int l = tid; l < BGR * (BGC / 4); l += 256) {
        int r = l / (BGC / 4), c4 = (l % (BGC / 4)) * 4;
        int iy = y0 + r, ix = x0 + c4;
        float4 v = make_float4(0.f, 0.f, 0.f, 0.f);
        if (iy < HI && ix < WI) v = *(const float4*)(img + iy * WI + ix);
        unsigned short h[4], lo[4];
        float vv[4] = {v.x, v.y, v.z, v.w};
        #pragma unroll
        for (int e = 0; e < 4; ++e) {
            h[e] = f2bf(vv[e]);
            lo[e] = f2bf(vv[e] - bf2f(h[e]));
        }
        *(uint2*)&S.m.bh[r][c4] = *(const uint2*)h;
        *(uint2*)&S.m.bl[r][c4] = *(const uint2*)lo;
    }

    // ---- build B shift-matrices in LDS (frag-major, conflict-free reads) ----
    for (int e = tid; e < 17 * 512; e += 256) {
        int i   = e >> 9;
        int rem = e & 511;
        int kc  = rem >> 7;          // k-chunk 0..3
        int n   = (rem >> 3) & 15;
        int e8  = rem & 7;
        int j   = kc * 8 + e8 - n;   // kk - n
        float val = (j >= 0 && j < 17) ? tp[i * TPAD + j] : 0.f;
        unsigned short h = f2bf(val);
        S.m.Bh[e] = h;
        S.m.Bl[e] = f2bf(val - bf2f(h));
    }
    __syncthreads();

    // ---- main loop: 17 template rows x (2M x 2N tiles) x 3 split-MFMAs ----
    f32x4 accM[2][2] = {};   // hi*hi
    f32x4 accC[2][2] = {};   // hi*lo + lo*hi
    for (int i = 0; i < HT; ++i) {
        int bb = i * 512 + lk * 128 + lm * 8;
        bf16x8 Bh_ = *(const bf16x8*)&S.m.Bh[bb];
        bf16x8 Bl_ = *(const bf16x8*)&S.m.Bl[bb];
        #pragma unroll
        for (int mt = 0; mt < 2; ++mt) {
            int row = y0w + mt * 16 + lm + i;
            #pragma unroll
            for (int nt = 0; nt < 2; ++nt) {
                int col = x0w + nt * 16 + lk * 8;
                bf16x8 Ah = *(const bf16x8*)&S.m.bh[row][col];
                bf16x8 Al = *(const bf16x8*)&S.m.bl[row][col];
                accM[mt][nt] = __builtin_amdgcn_mfma_f32_16x16x32_bf16(
                    Ah, Bh_, accM[mt][nt], 0, 0, 0);
                accC[mt][nt] = __builtin_amdgcn_mfma_f32_16x16x32_bf16(
                    Ah, Bl_, accC[mt][nt], 0, 0, 0);
                accC[mt][nt] = __builtin_amdgcn_mfma_f32_16x16x32_bf16(
                    Al, Bh_, accC[mt][nt], 0, 0, 0);
            }
        }
    }
    __syncthreads();   // main loop done everywhere; B region free for overlay

    // ---- r1: horizontal 17-sums of bg (hi+lo reconstruct), overlay on B ----
    for (int task = tid; task < BGR * 2; task += 256) {
        int r = task >> 1, xh = (task & 1) * 32;
        float s = 0.f;
        #pragma unroll
        for (int j = 0; j < HT; ++j)
            s += bf2f(S.m.bh[r][xh + j]) + bf2f(S.m.bl[r][xh + j]);
        S.s.r[r][xh] = s;
        for (int x = xh + 1; x < xh + 32; ++x) {
            s += bf2f(S.m.bh[r][x + 16]) + bf2f(S.m.bl[r][x + 16])
               - bf2f(S.m.bh[r][x - 1]) - bf2f(S.m.bl[r][x - 1]);
            S.s.r[r][x] = s;
        }
    }
    __syncthreads();
    float s1v[2][2][4];
    #pragma unroll
    for (int mt = 0; mt < 2; ++mt)
    #pragma unroll
    for (int nt = 0; nt < 2; ++nt) {
        int xcol = x0w + nt * 16 + lm;
        int yb = y0w + mt * 16 + lk * 4;
        float s = 0.f;
        #pragma unroll
        for (int ii = 0; ii < HT; ++ii) s += S.s.r[yb + ii][xcol];
        s1v[mt][nt][0] = s;
        #pragma unroll
        for (int q = 1; q < 4; ++q) {
            s += S.s.r[yb + q + 16][xcol] - S.s.r[yb + q - 1][xcol];
            s1v[mt][nt][q] = s;
        }
    }
    __syncthreads();

    // ---- r2: horizontal 17-sums of bg^2 ----
    for (int task = tid; task < BGR * 2; task += 256) {
        int r = task >> 1, xh = (task & 1) * 32;
        float s = 0.f;
        #pragma unroll
        for (int j = 0; j < HT; ++j) {
            float v = bf2f(S.m.bh[r][xh + j]) + bf2f(S.m.bl[r][xh + j]);
            s = fmaf(v, v, s);
        }
        S.s.r[r][xh] = s;
        for (int x = xh + 1; x < xh + 32; ++x) {
            float vn = bf2f(S.m.bh[r][x + 16]) + bf2f(S.m.bl[r][x + 16]);
            float vo = bf2f(S.m.bh[r][x - 1]) + bf2f(S.m.bl[r][x - 1]);
            s += vn * vn - vo * vo;
            S.s.r[r][x] = s;
        }
    }
    __syncthreads();
    float s2v[2][2][4];
    #pragma unroll
    for (int mt = 0; mt < 2; ++mt)
    #pragma unroll
    for (int nt = 0; nt < 2; ++nt) {
        int xcol = x0w + nt * 16 + lm;
        int yb = y0w + mt * 16 + lk * 4;
        float s = 0.f;
        #pragma unroll
        for (int ii = 0; ii < HT; ++ii) s += S.s.r[yb + ii][xcol];
        s2v[mt][nt][0] = s;
        #pragma unroll
        for (int q = 1; q < 4; ++q) {
            s += S.s.r[yb + q + 16][xcol] - S.s.r[yb + q - 1][xcol];
            s2v[mt][nt][q] = s;
        }
    }

    // ---- corr + masking ----
    const float invn = 1.0f / NTEMPL;
    float corr[2][2][4];
    float m = -INFINITY;
    #pragma unroll
    for (int mt = 0; mt < 2; ++mt)
    #pragma unroll
    for (int nt = 0; nt < 2; ++nt) {
        int ox = x0 + x0w + nt * 16 + lm;
        #pragma unroll
        for (int q = 0; q < 4; ++q) {
            int oy = y0 + y0w + mt * 16 + lk * 4 + q;
            float num = accM[mt][nt][q] + accC[mt][nt][q];
            float mu = s1v[mt][nt][q] * invn;
            float var = s2v[mt][nt][q] * invn - mu * mu;
            if (var < EPSV) var = EPSV;
            float cv = num / sqrtf(var);
            if (oy < LH && ox < LW) m = fmaxf(m, cv);
            else cv = -INFINITY;
            corr[mt][nt][q] = cv;
        }
    }

    // ---- block max ----
    float mm = m;
    #pragma unroll
    for (int o = 32; o > 0; o >>= 1) mm = fmaxf(mm, __shfl_down(mm, o, 64));
    if (lane == 0) redm[wid] = mm;
    __syncthreads();
    float M = fmaxf(fmaxf(redm[0], redm[1]), fmaxf(redm[2], redm[3]));

    // ---- partial softmax sums relative to tile max ----
    float l = 0.f, sy = 0.f, sx = 0.f;
    #pragma unroll
    for (int mt = 0; mt < 2; ++mt)
    #pragma unroll
    for (int nt = 0; nt < 2; ++nt) {
        int ox = x0 + x0w + nt * 16 + lm;
        #pragma unroll
        for (int q = 0; q < 4; ++q) {
            int oy = y0 + y0w + mt * 16 + lk * 4 + q;
            float cv = corr[mt][nt][q];
            float ev = (cv == -INFINITY) ? 0.f : __expf((cv - M) * TEMP_INV);
            l += ev;
            sy = fmaf(ev, (float)oy, sy);
            sx = fmaf(ev, (float)ox, sx);
        }
    }
    #pragma unroll
    for (int o = 32; o > 0; o >>= 1) {
        l  += __shfl_down(l, o, 64);
        sy += __shfl_down(sy, o, 64);
        sx += __shfl_down(sx, o, 64);
    }
    if (lane == 0) { redl[wid] = l; redy[wid] = sy; redx[wid] = sx; }
    __syncthreads();
    if (tid == 0) {
        float* p = partials + (size_t)blk * 4;
        p[0] = M;
        p[1] = redl[0] + redl[1] + redl[2] + redl[3];
        p[2] = redy[0] + redy[1] + redy[2] + redy[3];
        p[3] = redx[0] + redx[1] + redx[2] + redx[3];
    }
}

// ---------------- kernel 3: per-batch merge of tile partials ----------------
__global__ __launch_bounds__(256) void reduce_kernel(
    const float* __restrict__ partials, float* __restrict__ out) {
    int b = blockIdx.x;
    int tid = threadIdx.x;
    int wid = tid >> 6, lane = tid & 63;

    float m = -INFINITY, l = 0.f, sy = 0.f, sx = 0.f;
    if (tid < NTILES) {
        const float* p = partials + (size_t)(b * NTILES + tid) * 4;
        m = p[0]; l = p[1]; sy = p[2]; sx = p[3];
    }
    __shared__ float rm[4], rl[4], ry[4], rx[4];
    float mm = m;
    #pragma unroll
    for (int o = 32; o > 0; o >>= 1) mm = fmaxf(mm, __shfl_down(mm, o, 64));
    if (lane == 0) rm[wid] = mm;
    __syncthreads();
    float M = fmaxf(fmaxf(rm[0], rm[1]), fmaxf(rm[2], rm[3]));

    float sc = (m == -INFINITY) ? 0.f : __expf((m - M) * TEMP_INV);
    l *= sc; sy *= sc; sx *= sc;
    #pragma unroll
    for (int o = 32; o > 0; o >>= 1) {
        l  += __shfl_down(l, o, 64);
        sy += __shfl_down(sy, o, 64);
        sx += __shfl_down(sx, o, 64);
    }
    if (lane == 0) { rl[wid] = l; ry[wid] = sy; rx[wid] = sx; }
    __syncthreads();
    if (tid == 0) {
        float L  = rl[0] + rl[1] + rl[2] + rl[3];
        float SY = ry[0] + ry[1] + ry[2] + ry[3];
        float SX = rx[0] + rx[1] + rx[2] + rx[3];
        out[b * 2 + 0] = SX / L - 183.5f;
        out[b * 2 + 1] = SY / L - 183.5f;
        out[2 * NB + b] = M;
    }
}

extern "C" void kernel_launch(void* const* d_in, const int* in_sizes, int n_in,
                              void* d_out, int out_size, void* d_ws, size_t ws_size,
                              hipStream_t stream) {
    const float* piece = (const float*)d_in[0];   // [256,1,17,17]
    const float* bgg   = (const float*)d_in[1];   // [256,1,384,384]
    float* out = (float*)d_out;                   // 512 offsets + 256 max_corr

    float* tn = (float*)d_ws;                     // 256 * 340 floats
    float* partials = tn + NB * HT * TPAD;        // 256*36*4 floats

    tmpl_norm_kernel<<<NB, 256, 0, stream>>>(piece, tn);
    corr_kernel<<<NB * NTILES, 256, 0, stream>>>(bgg, tn, partials);
    reduce_kernel<<<NB, 256, 0, stream>>>(partials, out);
}